// Round 15
// baseline (856.682 us; speedup 1.0000x reference)
//
#include <hip/hip_runtime.h>

#define S_LEN 2048
#define HID   1152
#define HEADS 16
#define HD    72
#define ROT   36
#define LD3   3456   // 3*HID
#define FF    4304
#define FFP   4320   // FF padded to mult of 32

typedef short s16x8 __attribute__((ext_vector_type(8)));
typedef short s16x4 __attribute__((ext_vector_type(4)));
typedef float f32x4 __attribute__((ext_vector_type(4)));
typedef short bf_t;  // bf16 bit pattern

__device__ __forceinline__ short f2b(float f) {
  unsigned u = __float_as_uint(f);
  u += 0x7fffu + ((u >> 16) & 1u);   // RNE
  return (short)(u >> 16);
}
__device__ __forceinline__ float b2f(short h) {
  return __uint_as_float(((unsigned)(unsigned short)h) << 16);
}
__device__ __forceinline__ float gelu_f(float x) {
  float t = tanhf(0.7978845608028654f * (x + 0.044715f * x * x * x));
  return 0.5f * x * (1.0f + t);
}

// ---------------- weight arena (bf16 elems) ----------------
// qkv 3456x1152 | proj 1152x1152 | fc1 4352x1152 (rows 4304+ zero) | fc2 1152x4320
#define QKV_OFF 0
#define P_OFF   (3456 * 1152)
#define F1_OFF  (P_OFF + 1152 * 1152)
#define F2_OFF  (F1_OFF + 4352 * 1152)
#define ARENA_ELEMS (F2_OFF + 1152 * 4320)      // 15,298,560 elems = 30.6 MB
#define GA_Q  (8960 * 288)                       // group-A quads (K=1152 mats)
#define TOT_Q (GA_Q + 1152 * 1080)               // + fc2 quads

// one launch converts ALL 4 weight matrices of a layer (f32 -> bf16, padded)
__global__ __launch_bounds__(256) void convw_all(
    const float* __restrict__ qkvw, const float* __restrict__ projw,
    const float* __restrict__ fc1w, const float* __restrict__ fc2w,
    bf_t* __restrict__ arena)
{
  int idx = blockIdx.x * 256 + threadIdx.x;
  if (idx >= TOT_Q) return;
  if (idx < GA_Q) {                       // qkv | proj | fc1 : all K=1152
    int row = idx / 288, kq = (idx % 288) * 4;
    const float* s = nullptr; bf_t* d;
    if (row < 3456)      { s = qkvw + (size_t)row * 1152;  d = arena + (size_t)row * 1152; }
    else if (row < 4608) { int r = row - 3456; s = projw + (size_t)r * 1152; d = arena + P_OFF + (size_t)r * 1152; }
    else                 { int r = row - 4608; d = arena + F1_OFF + (size_t)r * 1152;
                           if (r < FF) s = fc1w + (size_t)r * 1152; }
    s16x4 o;
    if (s) { float4 v = *(const float4*)(s + kq);
             o[0] = f2b(v.x); o[1] = f2b(v.y); o[2] = f2b(v.z); o[3] = f2b(v.w); }
    else   { o[0] = 0; o[1] = 0; o[2] = 0; o[3] = 0; }
    *(s16x4*)(d + kq) = o;
  } else {                                // fc2: 1152 rows x 4304 -> pad cols to 4320
    int q = idx - GA_Q;
    int r = q / 1080, kq = (q % 1080) * 4;
    s16x4 o;
    if (kq < FF) {                        // FF%4==0 so whole quad valid
      float4 v = *(const float4*)(fc2w + (size_t)r * FF + kq);
      o[0] = f2b(v.x); o[1] = f2b(v.y); o[2] = f2b(v.z); o[3] = f2b(v.w);
    } else { o[0] = 0; o[1] = 0; o[2] = 0; o[3] = 0; }
    *(s16x4*)(arena + F2_OFF + (size_t)r * FFP + kq) = o;
  }
}

// ---------------- cos/sin table ----------------
__global__ __launch_bounds__(256) void costab_kernel(
    const float* __restrict__ rot, float* __restrict__ ct, float* __restrict__ st)
{
  int i = blockIdx.x * 256 + threadIdx.x;
  if (i < S_LEN * ROT) { float f = rot[i]; ct[i] = cosf(f); st[i] = sinf(f); }
}

// ---------------- layernorm: f32 in -> bf16 out (layer-0 LN1 only) ---------
__global__ __launch_bounds__(256) void ln_kernel(
    const float* __restrict__ x, const float* __restrict__ wgt,
    const float* __restrict__ bia, bf_t* __restrict__ outb)
{
  const int row = blockIdx.x, tid = threadIdx.x;
  const float4* xr = (const float4*)(x + (size_t)row * HID);
  float4 a = xr[tid];
  float4 b2 = make_float4(0.f, 0.f, 0.f, 0.f);
  const bool has2 = tid < 32;
  if (has2) b2 = xr[256 + tid];
  float s = a.x + a.y + a.z + a.w + b2.x + b2.y + b2.z + b2.w;
  float q = a.x*a.x + a.y*a.y + a.z*a.z + a.w*a.w
          + b2.x*b2.x + b2.y*b2.y + b2.z*b2.z + b2.w*b2.w;
  for (int mk = 32; mk; mk >>= 1) { s += __shfl_xor(s, mk); q += __shfl_xor(q, mk); }
  __shared__ float red[16];
  if ((tid & 63) == 0) { red[tid >> 6] = s; red[8 + (tid >> 6)] = q; }
  __syncthreads();
  if (tid == 0) {
    red[4]  = red[0] + red[1] + red[2] + red[3];
    red[12] = red[8] + red[9] + red[10] + red[11];
  }
  __syncthreads();
  float mean = red[4] * (1.0f / HID);
  float var  = red[12] * (1.0f / HID) - mean * mean;
  float rstd = rsqrtf(var + 1e-6f);
  const float4* w4 = (const float4*)wgt;
  const float4* b4 = (const float4*)bia;
  s16x4* o4 = (s16x4*)(outb + (size_t)row * HID);
  {
    float4 wv = w4[tid], bv = b4[tid];
    s16x4 o;
    o[0] = f2b((a.x - mean) * rstd * wv.x + bv.x);
    o[1] = f2b((a.y - mean) * rstd * wv.y + bv.y);
    o[2] = f2b((a.z - mean) * rstd * wv.z + bv.z);
    o[3] = f2b((a.w - mean) * rstd * wv.w + bv.w);
    o4[tid] = o;
  }
  if (has2) {
    float4 wv = w4[256 + tid], bv = b4[256 + tid];
    s16x4 o;
    o[0] = f2b((b2.x - mean) * rstd * wv.x + bv.x);
    o[1] = f2b((b2.y - mean) * rstd * wv.y + bv.y);
    o[2] = f2b((b2.z - mean) * rstd * wv.z + bv.z);
    o[3] = f2b((b2.w - mean) * rstd * wv.w + bv.w);
    o4[256 + tid] = o;
  }
}

// ------- fused split-K reduce (+bias+resid) -> xout f32, optional LN -> bf16
__global__ __launch_bounds__(256) void redln_kernel(
    const float* __restrict__ part, const float* __restrict__ bias,
    const float* __restrict__ resid, float* __restrict__ xout,
    bf_t* __restrict__ hout, const float* __restrict__ lnw,
    const float* __restrict__ lnb, int do_ln)
{
  const int row = blockIdx.x, tid = threadIdx.x;
  const size_t base = (size_t)row * 288;
  const float4* r4 = (const float4*)resid;
  const float4* b4 = (const float4*)bias;
  const float4* p4 = (const float4*)part;
  const bool has2 = tid < 32;

  float4 a, c;
  {
    float4 r = r4[base + tid], bv = b4[tid];
    a = make_float4(r.x + bv.x, r.y + bv.y, r.z + bv.z, r.w + bv.w);
#pragma unroll
    for (int p = 0; p < 4; p++) {
      float4 v = p4[(size_t)p * S_LEN * 288 + base + tid];
      a.x += v.x; a.y += v.y; a.z += v.z; a.w += v.w;
    }
  }
  c = make_float4(0.f, 0.f, 0.f, 0.f);
  if (has2) {
    float4 r = r4[base + 256 + tid], bv = b4[256 + tid];
    c = make_float4(r.x + bv.x, r.y + bv.y, r.z + bv.z, r.w + bv.w);
#pragma unroll
    for (int p = 0; p < 4; p++) {
      float4 v = p4[(size_t)p * S_LEN * 288 + base + 256 + tid];
      c.x += v.x; c.y += v.y; c.z += v.z; c.w += v.w;
    }
  }
  ((float4*)xout)[base + tid] = a;
  if (has2) ((float4*)xout)[base + 256 + tid] = c;

  if (!do_ln) return;

  float s = a.x + a.y + a.z + a.w + c.x + c.y + c.z + c.w;
  float q = a.x*a.x + a.y*a.y + a.z*a.z + a.w*a.w
          + c.x*c.x + c.y*c.y + c.z*c.z + c.w*c.w;
  for (int mk = 32; mk; mk >>= 1) { s += __shfl_xor(s, mk); q += __shfl_xor(q, mk); }
  __shared__ float red[16];
  if ((tid & 63) == 0) { red[tid >> 6] = s; red[8 + (tid >> 6)] = q; }
  __syncthreads();
  if (tid == 0) {
    red[4]  = red[0] + red[1] + red[2] + red[3];
    red[12] = red[8] + red[9] + red[10] + red[11];
  }
  __syncthreads();
  float mean = red[4] * (1.0f / HID);
  float var  = red[12] * (1.0f / HID) - mean * mean;
  float rstd = rsqrtf(var + 1e-6f);
  const float4* w4 = (const float4*)lnw;
  const float4* lb4 = (const float4*)lnb;
  s16x4* o4 = (s16x4*)(hout + (size_t)row * HID);
  {
    float4 wv = w4[tid], bv = lb4[tid];
    s16x4 o;
    o[0] = f2b((a.x - mean) * rstd * wv.x + bv.x);
    o[1] = f2b((a.y - mean) * rstd * wv.y + bv.y);
    o[2] = f2b((a.z - mean) * rstd * wv.z + bv.z);
    o[3] = f2b((a.w - mean) * rstd * wv.w + bv.w);
    o4[tid] = o;
  }
  if (has2) {
    float4 wv = w4[256 + tid], bv = lb4[256 + tid];
    s16x4 o;
    o[0] = f2b((c.x - mean) * rstd * wv.x + bv.x);
    o[1] = f2b((c.y - mean) * rstd * wv.y + bv.y);
    o[2] = f2b((c.z - mean) * rstd * wv.z + bv.z);
    o[3] = f2b((c.w - mean) * rstd * wv.w + bv.w);
    o4[256 + tid] = o;
  }
}

// ---------------- rotary in-place on qkv (bf16), q pre-scaled ----------------
__global__ __launch_bounds__(256) void rotary_kernel(
    bf_t* __restrict__ qkv, const float* __restrict__ ct, const float* __restrict__ st)
{
  int idx = blockIdx.x * 256 + threadIdx.x;
  if (idx >= S_LEN * HEADS * ROT) return;
  int t = idx / (HEADS * ROT);
  int r = idx % (HEADS * ROT);
  int h = r / ROT, dd = r % ROT;
  float c = ct[t * ROT + dd], s = st[t * ROT + dd];
  size_t base = (size_t)t * LD3 + h * HD + dd;
  float q1 = b2f(qkv[base]),        q2 = b2f(qkv[base + ROT]);
  float k1 = b2f(qkv[base + HID]),  k2 = b2f(qkv[base + HID + ROT]);
  const float scale = 0.11785113019775793f; // 1/sqrt(72)
  qkv[base]             = f2b((q1 * c - q2 * s) * scale);
  qkv[base + ROT]       = f2b((q2 * c + q1 * s) * scale);
  qkv[base + HID]       = f2b(k1 * c - k2 * s);
  qkv[base + HID + ROT] = f2b(k2 * c + k1 * s);
}

// ============ gemm_direct: BM=128, BN=64, NO LDS, NO barriers ===============
// Each wave loads its A/B fragments global->register directly (per-lane 16B,
// 16x64B lines per instr). Compiler software-pipelines loads across K-iters
// with counted vmcnt (m97 implicit-overlap mechanism, minus barrier drain).
// A halves shared by 2 waves (2x A traffic), B halves by 2 waves (2x B) --
// 24KB/block-iter through L2 (~half the L2 ceiling at target speed).
// MODE 0: bf16 = acc + bias
// MODE 2: bf16 = gelu(acc+bias) for cc<nvalid; 0 for nvalid<=cc<ldc; skip >=ldc
// MODE 3: f32 partial = acc at part + bz*S_LEN*ldc (split-K)
template<int MODE>
__global__ __launch_bounds__(256, 4) void gemm_direct(
    const bf_t* __restrict__ A, int lda,
    const bf_t* __restrict__ B, int ldb,
    const float* __restrict__ bias, int nbias,
    void* outp, int ldc, int nvalid, int K, int kchunk)
{
  const int tid = threadIdx.x;
  const int l = tid & 63, w = tid >> 6;
  const int lr = l & 15, lg = l >> 4;
  const int wm = (w >> 1) * 64, wn = (w & 1) * 32;

  // bijective XCD-aware swizzle over flattened grid (all grids are %8==0)
  unsigned gx = gridDim.x, gy = gridDim.y, gz = gridDim.z;
  unsigned nwg = gx * gy * gz;
  unsigned lin = (blockIdx.z * gy + blockIdx.y) * gx + blockIdx.x;
  if ((nwg & 7u) == 0u) {
    unsigned q = nwg >> 3;
    lin = (lin & 7u) * q + (lin >> 3);
  }
  const unsigned bz = lin / (gx * gy);
  const unsigned rem = lin % (gx * gy);
  const unsigned by = rem / gx, bx = rem % gx;

  const int rowA0 = by * 128, colB0 = bx * 64;
  const int kb0 = bz * kchunk;
  int kb1 = kb0 + kchunk; if (kb1 > K) kb1 = K;

  // per-lane fragment base pointers (advance by 32 elems per iter)
  const bf_t* ap[4];
  const bf_t* bp[2];
#pragma unroll
  for (int mt = 0; mt < 4; mt++)
    ap[mt] = A + (size_t)(rowA0 + wm + mt * 16 + lr) * lda + kb0 + lg * 8;
#pragma unroll
  for (int nt = 0; nt < 2; nt++)
    bp[nt] = B + (size_t)(colB0 + wn + nt * 16 + lr) * ldb + kb0 + lg * 8;

  f32x4 acc[4][2] = {};

  for (int kb = kb0; kb < kb1; kb += 32) {
    s16x8 af[4], bv[2];
#pragma unroll
    for (int mt = 0; mt < 4; mt++) { af[mt] = *(const s16x8*)ap[mt]; ap[mt] += 32; }
#pragma unroll
    for (int nt = 0; nt < 2; nt++) { bv[nt] = *(const s16x8*)bp[nt]; bp[nt] += 32; }
#pragma unroll
    for (int mt = 0; mt < 4; mt++)
#pragma unroll
      for (int nt = 0; nt < 2; nt++)
        acc[mt][nt] = __builtin_amdgcn_mfma_f32_16x16x32_bf16(af[mt], bv[nt], acc[mt][nt], 0, 0, 0);
  }

#pragma unroll
  for (int mt = 0; mt < 4; mt++) {
    const int rr = rowA0 + wm + mt * 16 + lg * 4;
#pragma unroll
    for (int nt = 0; nt < 2; nt++) {
      const int cc = colB0 + wn + nt * 16 + lr;
      if (MODE == 2 && cc >= ldc) continue;
      const float bvl = (MODE == 3) ? 0.0f : ((cc < nbias) ? bias[cc] : 0.0f);
#pragma unroll
      for (int i = 0; i < 4; i++) {
        float v = acc[mt][nt][i] + bvl;
        const int row = rr + i;
        if (MODE == 0) {
          ((bf_t*)outp)[(size_t)row * ldc + cc] = f2b(v);
        } else if (MODE == 2) {
          if (cc < nvalid)      ((bf_t*)outp)[(size_t)row * ldc + cc] = f2b(gelu_f(v));
          else                  ((bf_t*)outp)[(size_t)row * ldc + cc] = 0;
        } else { // MODE 3
          float* P = (float*)outp + (size_t)bz * ((size_t)S_LEN * ldc);
          P[(size_t)row * ldc + cc] = v;
        }
      }
    }
  }
}

// ---------------- flash attention v3 (R14-exact): QBLK=128, 8 waves ---------
#define QSTR 104
#define VSTR 76
#define PSTR 72
__global__ __launch_bounds__(512, 2) void attn_kernel(
    const bf_t* __restrict__ qkv, const int* __restrict__ cu, int nseg,
    bf_t* __restrict__ outb)
{
  __shared__ __align__(16) bf_t Qs[128 * QSTR];
  __shared__ __align__(16) bf_t Ks[2][64 * QSTR];
  __shared__ __align__(16) bf_t VTs[2][80 * VSTR];
  __shared__ __align__(16) bf_t Pb[8][16 * PSTR];
  const int tid = threadIdx.x;
  const int l = tid & 63, w = tid >> 6;      // 8 waves
  const int lr = l & 15, lg = l >> 4;
  const int h = blockIdx.y;
  const int qbase = blockIdx.x * 128;

  int kstart = 0, kend = S_LEN;
  for (int s2 = 0; s2 < nseg; s2++) {
    int a = cu[s2], b = cu[s2 + 1];
    if (qbase >= a && qbase < b) { kstart = a; kend = b; }
  }

  for (int i = tid; i < 128 * QSTR; i += 512)
    if ((i % QSTR) >= HD) Qs[i] = 0;
  for (int i = tid; i < 64 * QSTR; i += 512)
    if ((i % QSTR) >= HD) { Ks[0][i] = 0; Ks[1][i] = 0; }
  for (int i = tid; i < 80 * VSTR; i += 512)
    if ((i / VSTR) >= HD) { VTs[0][i] = 0; VTs[1][i] = 0; }
  for (int c = tid; c < 1152; c += 512) {
    int r = c / 9, j = c % 9;
    *(s16x8*)&Qs[r * QSTR + j * 8] =
        *(const s16x8*)&qkv[(size_t)(qbase + r) * LD3 + h * HD + j * 8];
  }
  {
#pragma unroll
    for (int u = 0; u < 2; u++) {
      int c = tid + u * 512;
      if (c < 576) {
        int r = c / 9, j = c % 9;
        int gr = kstart + r; if (gr >= kend) gr = kend - 1;
        *(s16x8*)&Ks[0][r * QSTR + j * 8] =
            *(const s16x8*)&qkv[(size_t)gr * LD3 + HID + h * HD + j * 8];
      }
    }
#pragma unroll
    for (int u = 0; u < 2; u++) {
      int c = tid + u * 512;
      if (c < 576) {
        int r = c & 63, j = c >> 6;
        int gr = kstart + r; if (gr >= kend) gr = kend - 1;
        s16x8 v = *(const s16x8*)&qkv[(size_t)gr * LD3 + 2 * HID + h * HD + j * 8];
#pragma unroll
        for (int jj = 0; jj < 8; jj++) VTs[0][(j * 8 + jj) * VSTR + r] = v[jj];
      }
    }
  }
  __syncthreads();

  s16x8 qf[3];
#pragma unroll
  for (int ks = 0; ks < 3; ks++)
    qf[ks] = *(const s16x8*)&Qs[(w * 16 + lr) * QSTR + ks * 32 + lg * 8];

  float m_i[4], l_i[4];
  f32x4 Of[5] = {};
#pragma unroll
  for (int i = 0; i < 4; i++) { m_i[i] = -1e30f; l_i[i] = 0.0f; }

  const int ntile = (kend - kstart + 63) >> 6;
  int cur = 0;
  for (int t = 0; t < ntile; t++) {
    const int kb = kstart + t * 64;
    const bool more = (t + 1 < ntile);

    s16x8 kreg[2], vreg[2];
    if (more) {
      const int nb = kb + 64;
#pragma unroll
      for (int u = 0; u < 2; u++) {
        int c = tid + u * 512;
        if (c < 576) {
          int r = c / 9, j = c % 9;
          int gr = nb + r; if (gr >= kend) gr = kend - 1;
          kreg[u] = *(const s16x8*)&qkv[(size_t)gr * LD3 + HID + h * HD + j * 8];
        }
      }
#pragma unroll
      for (int u = 0; u < 2; u++) {
        int c = tid + u * 512;
        if (c < 576) {
          int r = c & 63, j = c >> 6;
          int gr = nb + r; if (gr >= kend) gr = kend - 1;
          vreg[u] = *(const s16x8*)&qkv[(size_t)gr * LD3 + 2 * HID + h * HD + j * 8];
        }
      }
    }

    f32x4 sc[4] = {};
#pragma unroll
    for (int kc = 0; kc < 4; kc++) {
#pragma unroll
      for (int ks = 0; ks < 3; ks++) {
        s16x8 kf = *(const s16x8*)&Ks[cur][(kc * 16 + lr) * QSTR + ks * 32 + lg * 8];
        sc[kc] = __builtin_amdgcn_mfma_f32_16x16x32_bf16(qf[ks], kf, sc[kc], 0, 0, 0);
      }
    }
#pragma unroll
    for (int kc = 0; kc < 4; kc++) {
      if ((kb + kc * 16 + lr) >= kend) {
#pragma unroll
        for (int i = 0; i < 4; i++) sc[kc][i] = -1e30f;
      }
    }
    float tmax[4], scl[4], rs[4];
#pragma unroll
    for (int i = 0; i < 4; i++) {
      float tm = fmaxf(fmaxf(sc[0][i], sc[1][i]), fmaxf(sc[2][i], sc[3][i]));
#pragma unroll
      for (int d2 = 1; d2 < 16; d2 <<= 1) tm = fmaxf(tm, __shfl_xor(tm, d2));
      tmax[i] = tm;
    }
#pragma unroll
    for (int i = 0; i < 4; i++) {
      float mn = fmaxf(m_i[i], tmax[i]);
      scl[i] = __expf(m_i[i] - mn);
      m_i[i] = mn;
      rs[i] = 0.0f;
    }
#pragma unroll
    for (int kc = 0; kc < 4; kc++)
#pragma unroll
      for (int i = 0; i < 4; i++) {
        float p = __expf(sc[kc][i] - m_i[i]);
        sc[kc][i] = p;
        rs[i] += p;
      }
#pragma unroll
    for (int i = 0; i < 4; i++) {
#pragma unroll
      for (int d2 = 1; d2 < 16; d2 <<= 1) rs[i] += __shfl_xor(rs[i], d2);
      l_i[i] = l_i[i] * scl[i] + rs[i];
    }
#pragma unroll
    for (int nt = 0; nt < 5; nt++)
#pragma unroll
      for (int i = 0; i < 4; i++) Of[nt][i] *= scl[i];
#pragma unroll
    for (int kc = 0; kc < 4; kc++)
#pragma unroll
      for (int i = 0; i < 4; i++)
        Pb[w][(lg * 4 + i) * PSTR + kc * 16 + lr] = f2b(sc[kc][i]);
    asm volatile("s_waitcnt lgkmcnt(0)" ::: "memory");
    __builtin_amdgcn_sched_barrier(0);
    s16x8 pf[2];
#pragma unroll
    for (int k2 = 0; k2 < 2; k2++)
      pf[k2] = *(const s16x8*)&Pb[w][lr * PSTR + k2 * 32 + lg * 8];
#pragma unroll
    for (int nt = 0; nt < 5; nt++) {
#pragma unroll
      for (int k2 = 0; k2 < 2; k2++) {
        const int vb = (nt * 16 + lr) * VSTR + k2 * 32 + lg * 8;
        s16x4 va = *(const s16x4*)&VTs[cur][vb];
        s16x4 vb2 = *(const s16x4*)&VTs[cur][vb + 4];
        s16x8 vf;
        vf[0] = va[0]; vf[1] = va[1]; vf[2] = va[2]; vf[3] = va[3];
        vf[4] = vb2[0]; vf[5] = vb2[1]; vf[6] = vb2[2]; vf[7] = vb2[3];
        Of[nt] = __builtin_amdgcn_mfma_f32_16x16x32_bf16(pf[k2], vf, Of[nt], 0, 0, 0);
      }
    }

    if (more) {
#pragma unroll
      for (int u = 0; u < 2; u++) {
        int c = tid + u * 512;
        if (c < 576) {
          int r = c / 9, j = c % 9;
          *(s16x8*)&Ks[cur ^ 1][r * QSTR + j * 8] = kreg[u];
        }
      }
#pragma unroll
      for (int u = 0; u < 2; u++) {
        int c = tid + u * 512;
        if (c < 576) {
          int r = c & 63, j = c >> 6;
#pragma unroll
          for (int jj = 0; jj < 8; jj++)
            VTs[cur ^ 1][(j * 8 + jj) * VSTR + r] = vreg[u][jj];
        }
      }
    }
    __syncthreads();
    cur ^= 1;
  }

  float inv[4];
#pragma unroll
  for (int i = 0; i < 4; i++) inv[i] = 1.0f / l_i[i];
#pragma unroll
  for (int nt = 0; nt < 5; nt++) {
    int cc = nt * 16 + lr;
    if (cc < HD) {
#pragma unroll
      for (int i = 0; i < 4; i++) {
        int row = qbase + w * 16 + lg * 4 + i;
        outb[(size_t)row * HID + h * HD + cc] = f2b(Of[nt][i] * inv[i]);
      }
    }
  }
}

// ---------------- host orchestration ----------------
extern "C" void kernel_launch(void* const* d_in, const int* in_sizes, int n_in,
                              void* d_out, int out_size, void* d_ws, size_t ws_size,
                              hipStream_t stream) {
  const float* x     = (const float*)d_in[0];
  const int*   cu    = (const int*)d_in[1];
  const float* rotab = (const float*)d_in[2];
  const float* n1w   = (const float*)d_in[3];
  const float* n1b   = (const float*)d_in[4];
  const float* qkvw  = (const float*)d_in[5];
  const float* qkvb  = (const float*)d_in[6];
  const float* projw = (const float*)d_in[7];
  const float* projb = (const float*)d_in[8];
  const float* n2w   = (const float*)d_in[9];
  const float* n2b   = (const float*)d_in[10];
  const float* fc1w  = (const float*)d_in[11];
  const float* fc1b  = (const float*)d_in[12];
  const float* fc2w  = (const float*)d_in[13];
  const float* fc2b  = (const float*)d_in[14];
  float* out = (float*)d_out;
  char* ws = (char*)d_ws;

  size_t off = 0;
  float* xbuf = (float*)(ws + off); off += (size_t)S_LEN * HID * 4;        // 9.44 MB
  bf_t* hbf   = (bf_t*)(ws + off);  off += (size_t)S_LEN * HID * 2;        // 4.72 MB
  bf_t* qkvbf = (bf_t*)(ws + off);                                          // shared slot
  bf_t* ff1bf = (bf_t*)(ws + off);  off += (size_t)S_LEN * FFP * 2;        // 17.7 MB
  bf_t* attnbf= (bf_t*)(ws + off);  off += (size_t)S_LEN * HID * 2;        // 4.72 MB
  bf_t* arena = (bf_t*)(ws + off);  off += (size_t)ARENA_ELEMS * 2;        // 30.6 MB
  float* ctab = (float*)(ws + off); off += (size_t)S_LEN * ROT * 4;
  float* stab = (float*)(ws + off); off += (size_t)S_LEN * ROT * 4;
  float* part = (float*)(ws + off); off += (size_t)4 * S_LEN * HID * 4;    // 37.75 MB

  costab_kernel<<<(S_LEN * ROT + 255) / 256, 256, 0, stream>>>(rotab, ctab, stab);

  const int nseg = in_sizes[1] - 1;

  for (int d = 0; d < 2; d++) {
    const float* xin = (d == 0) ? x : xbuf;   // residual spine source
    convw_all<<<(TOT_Q + 255) / 256, 256, 0, stream>>>(
        qkvw + (size_t)d * LD3 * HID, projw + (size_t)d * HID * HID,
        fc1w + (size_t)d * FF * HID, fc2w + (size_t)d * HID * FF, arena);
    if (d == 0)
      ln_kernel<<<S_LEN, 256, 0, stream>>>(x, n1w, n1b, hbf);
    // QKV: direct, grid 54x16 = 864 blocks
    gemm_direct<0><<<dim3(LD3 / 64, 16), 256, 0, stream>>>(
        hbf, HID, arena + QKV_OFF, HID, qkvb + (size_t)d * LD3, LD3,
        qkvbf, LD3, LD3, HID, HID);
    rotary_kernel<<<(S_LEN * HEADS * ROT + 255) / 256, 256, 0, stream>>>(qkvbf, ctab, stab);
    // attention: QBLK=128, grid 16x16 = 256 blocks (1/CU)
    attn_kernel<<<dim3(S_LEN / 128, HEADS), 512, 0, stream>>>(qkvbf, cu, nseg, attnbf);
    // proj: direct split-K x4 (kchunk 288), grid 18x16x4 = 1152
    gemm_direct<3><<<dim3(HID / 64, 16, 4), 256, 0, stream>>>(
        attnbf, HID, arena + P_OFF, HID, nullptr, 0, part, HID, HID, HID, 288);
    redln_kernel<<<S_LEN, 256, 0, stream>>>(
        part, projb + (size_t)d * HID, xin, xbuf, hbf,
        n2w + (size_t)d * HID, n2b + (size_t)d * HID, 1);
    // FC1 (+gelu): direct, grid 68x16 = 1088 (ceil(4320/64)=68; B padded to 4352 rows)
    gemm_direct<2><<<dim3((FFP + 63) / 64, 16), 256, 0, stream>>>(
        hbf, HID, arena + F1_OFF, HID, fc1b + (size_t)d * FF, FF,
        ff1bf, FFP, FF, HID, HID);
    // FC2: direct split-K x4 (K=4320, kchunk 1088), grid 18x16x4 = 1152
    gemm_direct<3><<<dim3(HID / 64, 16, 4), 256, 0, stream>>>(
        ff1bf, FFP, arena + F2_OFF, FFP, nullptr, 0, part, HID, HID, FFP, 1088);
    if (d == 0) {
      redln_kernel<<<S_LEN, 256, 0, stream>>>(
          part, fc2b, xbuf, xbuf, hbf, n1w + HID, n1b + HID, 1);
    } else {
      redln_kernel<<<S_LEN, 256, 0, stream>>>(
          part, fc2b + (size_t)HID, xbuf, out, nullptr, nullptr, nullptr, 0);
    }
  }
}

// Round 16
// 400.754 us; speedup vs baseline: 2.1377x; 2.1377x over previous
//
#include <hip/hip_runtime.h>

#define S_LEN 2048
#define HID   1152
#define HEADS 16
#define HD    72
#define ROT   36
#define LD3   3456   // 3*HID
#define FF    4304
#define FFP   4320   // FF padded to mult of 32

typedef short s16x8 __attribute__((ext_vector_type(8)));
typedef short s16x4 __attribute__((ext_vector_type(4)));
typedef float f32x4 __attribute__((ext_vector_type(4)));
typedef short bf_t;  // bf16 bit pattern

__device__ __forceinline__ short f2b(float f) {
  unsigned u = __float_as_uint(f);
  u += 0x7fffu + ((u >> 16) & 1u);   // RNE
  return (short)(u >> 16);
}
__device__ __forceinline__ float b2f(short h) {
  return __uint_as_float(((unsigned)(unsigned short)h) << 16);
}
__device__ __forceinline__ float gelu_f(float x) {
  float t = tanhf(0.7978845608028654f * (x + 0.044715f * x * x * x));
  return 0.5f * x * (1.0f + t);
}

typedef const __attribute__((address_space(1))) void* gas_p;
typedef __attribute__((address_space(3))) void* las_p;
__device__ __forceinline__ void gload16(const void* g, void* l) {
  __builtin_amdgcn_global_load_lds((gas_p)g, (las_p)l, 16, 0, 0);
}

// ---------------- weight arena (bf16 elems) ----------------
// qkv 3456x1152 | proj 1152x1152 | fc1 4352x1152 (rows 4304+ zero) | fc2 1152x4320
#define QKV_OFF 0
#define P_OFF   (3456 * 1152)
#define F1_OFF  (P_OFF + 1152 * 1152)
#define F2_OFF  (F1_OFF + 4352 * 1152)
#define ARENA_ELEMS (F2_OFF + 1152 * 4320)      // 15,298,560 elems = 30.6 MB
#define GA_Q  (8960 * 288)                       // group-A quads (K=1152 mats)
#define TOT_Q (GA_Q + 1152 * 1080)               // + fc2 quads

// one launch converts ALL 4 weight matrices of a layer (f32 -> bf16, padded)
__global__ __launch_bounds__(256) void convw_all(
    const float* __restrict__ qkvw, const float* __restrict__ projw,
    const float* __restrict__ fc1w, const float* __restrict__ fc2w,
    bf_t* __restrict__ arena)
{
  int idx = blockIdx.x * 256 + threadIdx.x;
  if (idx >= TOT_Q) return;
  if (idx < GA_Q) {                       // qkv | proj | fc1 : all K=1152
    int row = idx / 288, kq = (idx % 288) * 4;
    const float* s = nullptr; bf_t* d;
    if (row < 3456)      { s = qkvw + (size_t)row * 1152;  d = arena + (size_t)row * 1152; }
    else if (row < 4608) { int r = row - 3456; s = projw + (size_t)r * 1152; d = arena + P_OFF + (size_t)r * 1152; }
    else                 { int r = row - 4608; d = arena + F1_OFF + (size_t)r * 1152;
                           if (r < FF) s = fc1w + (size_t)r * 1152; }
    s16x4 o;
    if (s) { float4 v = *(const float4*)(s + kq);
             o[0] = f2b(v.x); o[1] = f2b(v.y); o[2] = f2b(v.z); o[3] = f2b(v.w); }
    else   { o[0] = 0; o[1] = 0; o[2] = 0; o[3] = 0; }
    *(s16x4*)(d + kq) = o;
  } else {                                // fc2: 1152 rows x 4304 -> pad cols to 4320
    int q = idx - GA_Q;
    int r = q / 1080, kq = (q % 1080) * 4;
    s16x4 o;
    if (kq < FF) {                        // FF%4==0 so whole quad valid
      float4 v = *(const float4*)(fc2w + (size_t)r * FF + kq);
      o[0] = f2b(v.x); o[1] = f2b(v.y); o[2] = f2b(v.z); o[3] = f2b(v.w);
    } else { o[0] = 0; o[1] = 0; o[2] = 0; o[3] = 0; }
    *(s16x4*)(arena + F2_OFF + (size_t)r * FFP + kq) = o;
  }
}

// ---------------- cos/sin table ----------------
__global__ __launch_bounds__(256) void costab_kernel(
    const float* __restrict__ rot, float* __restrict__ ct, float* __restrict__ st)
{
  int i = blockIdx.x * 256 + threadIdx.x;
  if (i < S_LEN * ROT) { float f = rot[i]; ct[i] = cosf(f); st[i] = sinf(f); }
}

// ---------------- layernorm: f32 in -> bf16 out (layer-0 LN1 only) ---------
__global__ __launch_bounds__(256) void ln_kernel(
    const float* __restrict__ x, const float* __restrict__ wgt,
    const float* __restrict__ bia, bf_t* __restrict__ outb)
{
  const int row = blockIdx.x, tid = threadIdx.x;
  const float4* xr = (const float4*)(x + (size_t)row * HID);
  float4 a = xr[tid];
  float4 b2 = make_float4(0.f, 0.f, 0.f, 0.f);
  const bool has2 = tid < 32;
  if (has2) b2 = xr[256 + tid];
  float s = a.x + a.y + a.z + a.w + b2.x + b2.y + b2.z + b2.w;
  float q = a.x*a.x + a.y*a.y + a.z*a.z + a.w*a.w
          + b2.x*b2.x + b2.y*b2.y + b2.z*b2.z + b2.w*b2.w;
  for (int mk = 32; mk; mk >>= 1) { s += __shfl_xor(s, mk); q += __shfl_xor(q, mk); }
  __shared__ float red[16];
  if ((tid & 63) == 0) { red[tid >> 6] = s; red[8 + (tid >> 6)] = q; }
  __syncthreads();
  if (tid == 0) {
    red[4]  = red[0] + red[1] + red[2] + red[3];
    red[12] = red[8] + red[9] + red[10] + red[11];
  }
  __syncthreads();
  float mean = red[4] * (1.0f / HID);
  float var  = red[12] * (1.0f / HID) - mean * mean;
  float rstd = rsqrtf(var + 1e-6f);
  const float4* w4 = (const float4*)wgt;
  const float4* b4 = (const float4*)bia;
  s16x4* o4 = (s16x4*)(outb + (size_t)row * HID);
  {
    float4 wv = w4[tid], bv = b4[tid];
    s16x4 o;
    o[0] = f2b((a.x - mean) * rstd * wv.x + bv.x);
    o[1] = f2b((a.y - mean) * rstd * wv.y + bv.y);
    o[2] = f2b((a.z - mean) * rstd * wv.z + bv.z);
    o[3] = f2b((a.w - mean) * rstd * wv.w + bv.w);
    o4[tid] = o;
  }
  if (has2) {
    float4 wv = w4[256 + tid], bv = b4[256 + tid];
    s16x4 o;
    o[0] = f2b((b2.x - mean) * rstd * wv.x + bv.x);
    o[1] = f2b((b2.y - mean) * rstd * wv.y + bv.y);
    o[2] = f2b((b2.z - mean) * rstd * wv.z + bv.z);
    o[3] = f2b((b2.w - mean) * rstd * wv.w + bv.w);
    o4[256 + tid] = o;
  }
}

// ------- fused split-K reduce (+bias+resid) -> xout f32, optional LN -> bf16
__global__ __launch_bounds__(256) void redln_kernel(
    const float* __restrict__ part, const float* __restrict__ bias,
    const float* __restrict__ resid, float* __restrict__ xout,
    bf_t* __restrict__ hout, const float* __restrict__ lnw,
    const float* __restrict__ lnb, int do_ln)
{
  const int row = blockIdx.x, tid = threadIdx.x;
  const size_t base = (size_t)row * 288;
  const float4* r4 = (const float4*)resid;
  const float4* b4 = (const float4*)bias;
  const float4* p4 = (const float4*)part;
  const bool has2 = tid < 32;

  float4 a, c;
  {
    float4 r = r4[base + tid], bv = b4[tid];
    a = make_float4(r.x + bv.x, r.y + bv.y, r.z + bv.z, r.w + bv.w);
#pragma unroll
    for (int p = 0; p < 4; p++) {
      float4 v = p4[(size_t)p * S_LEN * 288 + base + tid];
      a.x += v.x; a.y += v.y; a.z += v.z; a.w += v.w;
    }
  }
  c = make_float4(0.f, 0.f, 0.f, 0.f);
  if (has2) {
    float4 r = r4[base + 256 + tid], bv = b4[256 + tid];
    c = make_float4(r.x + bv.x, r.y + bv.y, r.z + bv.z, r.w + bv.w);
#pragma unroll
    for (int p = 0; p < 4; p++) {
      float4 v = p4[(size_t)p * S_LEN * 288 + base + 256 + tid];
      c.x += v.x; c.y += v.y; c.z += v.z; c.w += v.w;
    }
  }
  ((float4*)xout)[base + tid] = a;
  if (has2) ((float4*)xout)[base + 256 + tid] = c;

  if (!do_ln) return;

  float s = a.x + a.y + a.z + a.w + c.x + c.y + c.z + c.w;
  float q = a.x*a.x + a.y*a.y + a.z*a.z + a.w*a.w
          + c.x*c.x + c.y*c.y + c.z*c.z + c.w*c.w;
  for (int mk = 32; mk; mk >>= 1) { s += __shfl_xor(s, mk); q += __shfl_xor(q, mk); }
  __shared__ float red[16];
  if ((tid & 63) == 0) { red[tid >> 6] = s; red[8 + (tid >> 6)] = q; }
  __syncthreads();
  if (tid == 0) {
    red[4]  = red[0] + red[1] + red[2] + red[3];
    red[12] = red[8] + red[9] + red[10] + red[11];
  }
  __syncthreads();
  float mean = red[4] * (1.0f / HID);
  float var  = red[12] * (1.0f / HID) - mean * mean;
  float rstd = rsqrtf(var + 1e-6f);
  const float4* w4 = (const float4*)lnw;
  const float4* lb4 = (const float4*)lnb;
  s16x4* o4 = (s16x4*)(hout + (size_t)row * HID);
  {
    float4 wv = w4[tid], bv = lb4[tid];
    s16x4 o;
    o[0] = f2b((a.x - mean) * rstd * wv.x + bv.x);
    o[1] = f2b((a.y - mean) * rstd * wv.y + bv.y);
    o[2] = f2b((a.z - mean) * rstd * wv.z + bv.z);
    o[3] = f2b((a.w - mean) * rstd * wv.w + bv.w);
    o4[tid] = o;
  }
  if (has2) {
    float4 wv = w4[256 + tid], bv = lb4[256 + tid];
    s16x4 o;
    o[0] = f2b((c.x - mean) * rstd * wv.x + bv.x);
    o[1] = f2b((c.y - mean) * rstd * wv.y + bv.y);
    o[2] = f2b((c.z - mean) * rstd * wv.z + bv.z);
    o[3] = f2b((c.w - mean) * rstd * wv.w + bv.w);
    o4[256 + tid] = o;
  }
}

// ---------------- rotary in-place on qkv (bf16), q pre-scaled ----------------
__global__ __launch_bounds__(256) void rotary_kernel(
    bf_t* __restrict__ qkv, const float* __restrict__ ct, const float* __restrict__ st)
{
  int idx = blockIdx.x * 256 + threadIdx.x;
  if (idx >= S_LEN * HEADS * ROT) return;
  int t = idx / (HEADS * ROT);
  int r = idx % (HEADS * ROT);
  int h = r / ROT, dd = r % ROT;
  float c = ct[t * ROT + dd], s = st[t * ROT + dd];
  size_t base = (size_t)t * LD3 + h * HD + dd;
  float q1 = b2f(qkv[base]),        q2 = b2f(qkv[base + ROT]);
  float k1 = b2f(qkv[base + HID]),  k2 = b2f(qkv[base + HID + ROT]);
  const float scale = 0.11785113019775793f; // 1/sqrt(72)
  qkv[base]             = f2b((q1 * c - q2 * s) * scale);
  qkv[base + ROT]       = f2b((q2 * c + q1 * s) * scale);
  qkv[base + HID]       = f2b(k1 * c - k2 * s);
  qkv[base + HID + ROT] = f2b(k2 * c + k1 * s);
}

// ===== gemm1p (R6 gemm3-exact, MODE 3 only): BM=128,BN=128, 2-buf prefetch ==
// For split-K proj/fc2: f32 partial at part + bz*S_LEN*ldc
__global__ __launch_bounds__(256, 4) void gemm1p(
    const bf_t* __restrict__ A, int lda,
    const bf_t* __restrict__ B, int ldb,
    void* outp, int ldc, int K, int kchunk)
{
  __shared__ __align__(16) bf_t As[2][128 * 32];
  __shared__ __align__(16) bf_t Bs[2][128 * 32];
  const int tid = threadIdx.x;
  const int l = tid & 63, w = tid >> 6;
  const int lr = l & 15, lg = l >> 4;
  const int wm = (w >> 1) * 64, wn = (w & 1) * 64;

  unsigned gx = gridDim.x, gy = gridDim.y, gz = gridDim.z;
  unsigned nwg = gx * gy * gz;
  unsigned lin = (blockIdx.z * gy + blockIdx.y) * gx + blockIdx.x;
  if ((nwg & 7u) == 0u) {
    unsigned q = nwg >> 3;
    lin = (lin & 7u) * q + (lin >> 3);
  }
  const unsigned bz = lin / (gx * gy);
  const unsigned rem = lin % (gx * gy);
  const unsigned by = rem / gx, bx = rem % gx;

  const int rowA0 = by * 128, colB0 = bx * 128;
  const int kb0 = bz * kchunk;
  int kb1 = kb0 + kchunk; if (kb1 > K) kb1 = K;

  const int o1 = tid * 16, o2 = o1 + 4096;
  const int r1 = o1 >> 6, c1 = o1 & 63;
  const int r2 = r1 + 64;
  const char* Ab = (const char*)A;
  const char* Bb = (const char*)B;

#define STAGEP(buf, kk) do { \
    gload16(Ab + ((size_t)(rowA0 + r1) * lda + (kk)) * 2 + c1, (char*)As[buf] + o1); \
    gload16(Ab + ((size_t)(rowA0 + r2) * lda + (kk)) * 2 + c1, (char*)As[buf] + o2); \
    gload16(Bb + ((size_t)(colB0 + r1) * ldb + (kk)) * 2 + c1, (char*)Bs[buf] + o1); \
    gload16(Bb + ((size_t)(colB0 + r2) * ldb + (kk)) * 2 + c1, (char*)Bs[buf] + o2); \
  } while (0)

  f32x4 acc[4][4] = {};

  STAGEP(0, kb0);
  asm volatile("s_waitcnt vmcnt(0)" ::: "memory");
  __builtin_amdgcn_s_barrier();
  __builtin_amdgcn_sched_barrier(0);

  int cur = 0;
  for (int kb = kb0; kb < kb1; kb += 32) {
    if (kb + 32 < kb1) STAGEP(cur ^ 1, kb + 32);
    s16x8 af[4], bv[4];
#pragma unroll
    for (int mt = 0; mt < 4; mt++)
      af[mt] = *(const s16x8*)&As[cur][(wm + mt * 16 + lr) * 32 + lg * 8];
#pragma unroll
    for (int nt = 0; nt < 4; nt++)
      bv[nt] = *(const s16x8*)&Bs[cur][(wn + nt * 16 + lr) * 32 + lg * 8];
    asm volatile("s_waitcnt lgkmcnt(0)" ::: "memory");
    __builtin_amdgcn_sched_barrier(0);
#pragma unroll
    for (int mt = 0; mt < 4; mt++)
#pragma unroll
      for (int nt = 0; nt < 4; nt++)
        acc[mt][nt] = __builtin_amdgcn_mfma_f32_16x16x32_bf16(af[mt], bv[nt], acc[mt][nt], 0, 0, 0);
    asm volatile("s_waitcnt vmcnt(0)" ::: "memory");
    __builtin_amdgcn_s_barrier();
    __builtin_amdgcn_sched_barrier(0);
    cur ^= 1;
  }
#undef STAGEP

#pragma unroll
  for (int mt = 0; mt < 4; mt++) {
    const int rr = rowA0 + wm + mt * 16 + lg * 4;
#pragma unroll
    for (int nt = 0; nt < 4; nt++) {
      const int cc = colB0 + wn + nt * 16 + lr;
#pragma unroll
      for (int i = 0; i < 4; i++) {
        float* P = (float*)outp + (size_t)bz * ((size_t)S_LEN * ldc);
        P[(size_t)(rr + i) * ldc + cc] = acc[mt][nt][i];
      }
    }
  }
}

// ============ gemm2 (R3-exact): BM=128,BN=64, 2-buf prefetch ================
template<int MODE>
__global__ __launch_bounds__(256, 4) void gemm2(
    const bf_t* __restrict__ A, int lda,
    const bf_t* __restrict__ B, int ldb,
    const float* __restrict__ bias, int nbias,
    void* outp, int ldc, int nvalid, int K, int kchunk)
{
  __shared__ __align__(16) bf_t As[2][128 * 32];
  __shared__ __align__(16) bf_t Bs[2][64 * 32];
  const int tid = threadIdx.x;
  const int l = tid & 63, w = tid >> 6;
  const int lr = l & 15, lg = l >> 4;
  const int wm = (w >> 1) * 64, wn = (w & 1) * 32;

  unsigned gx = gridDim.x, gy = gridDim.y, gz = gridDim.z;
  unsigned nwg = gx * gy * gz;
  unsigned lin = (blockIdx.z * gy + blockIdx.y) * gx + blockIdx.x;
  if ((nwg & 7u) == 0u) {
    unsigned q = nwg >> 3;
    lin = (lin & 7u) * q + (lin >> 3);
  }
  const unsigned bz = lin / (gx * gy);
  const unsigned rem = lin % (gx * gy);
  const unsigned by = rem / gx, bx = rem % gx;

  const int rowA0 = by * 128, colB0 = bx * 64;
  const int kb0 = bz * kchunk;
  int kb1 = kb0 + kchunk; if (kb1 > K) kb1 = K;

  const int oA1 = tid * 16, oA2 = oA1 + 4096;
  const int rA1 = oA1 >> 6, cA1 = oA1 & 63;
  const int rA2 = rA1 + 64;
  const int oB = tid * 16;
  const int rB = oB >> 6, cB = oB & 63;
  const char* Ab = (const char*)A;
  const char* Bb = (const char*)B;

#define STAGE(buf, kk) do { \
    gload16(Ab + ((size_t)(rowA0 + rA1) * lda + (kk)) * 2 + cA1, (char*)As[buf] + oA1); \
    gload16(Ab + ((size_t)(rowA0 + rA2) * lda + (kk)) * 2 + cA1, (char*)As[buf] + oA2); \
    gload16(Bb + ((size_t)(colB0 + rB)  * ldb + (kk)) * 2 + cB,  (char*)Bs[buf] + oB);  \
  } while (0)

  f32x4 acc[4][2] = {};

  STAGE(0, kb0);
  asm volatile("s_waitcnt vmcnt(0)" ::: "memory");
  __builtin_amdgcn_s_barrier();
  __builtin_amdgcn_sched_barrier(0);

  int cur = 0;
  for (int kb = kb0; kb < kb1; kb += 32) {
    if (kb + 32 < kb1) STAGE(cur ^ 1, kb + 32);
    s16x8 af[4], bv[2];
#pragma unroll
    for (int mt = 0; mt < 4; mt++)
      af[mt] = *(const s16x8*)&As[cur][(wm + mt * 16 + lr) * 32 + lg * 8];
#pragma unroll
    for (int nt = 0; nt < 2; nt++)
      bv[nt] = *(const s16x8*)&Bs[cur][(wn + nt * 16 + lr) * 32 + lg * 8];
    asm volatile("s_waitcnt lgkmcnt(0)" ::: "memory");
    __builtin_amdgcn_sched_barrier(0);
#pragma unroll
    for (int mt = 0; mt < 4; mt++)
#pragma unroll
      for (int nt = 0; nt < 2; nt++)
        acc[mt][nt] = __builtin_amdgcn_mfma_f32_16x16x32_bf16(af[mt], bv[nt], acc[mt][nt], 0, 0, 0);
    asm volatile("s_waitcnt vmcnt(0)" ::: "memory");
    __builtin_amdgcn_s_barrier();
    __builtin_amdgcn_sched_barrier(0);
    cur ^= 1;
  }
#undef STAGE

#pragma unroll
  for (int mt = 0; mt < 4; mt++) {
    const int rr = rowA0 + wm + mt * 16 + lg * 4;
#pragma unroll
    for (int nt = 0; nt < 2; nt++) {
      const int cc = colB0 + wn + nt * 16 + lr;
      const float bvl = (cc < nbias) ? bias[cc] : 0.0f;
#pragma unroll
      for (int i = 0; i < 4; i++) {
        float v = acc[mt][nt][i] + bvl;
        const int row = rr + i;
        if (MODE == 0) {
          ((bf_t*)outp)[(size_t)row * ldc + cc] = f2b(v);
        } else if (MODE == 2) {
          if (cc < nvalid)      ((bf_t*)outp)[(size_t)row * ldc + cc] = f2b(gelu_f(v));
          else if (cc < ldc)    ((bf_t*)outp)[(size_t)row * ldc + cc] = 0;
        } else {
          float* P = (float*)outp + (size_t)bz * ((size_t)S_LEN * ldc);
          P[(size_t)row * ldc + cc] = v;
        }
      }
    }
  }
}

// ---------------- flash attention v3 (R14-exact): QBLK=128, 8 waves ---------
#define QSTR 104
#define VSTR 76
#define PSTR 72
__global__ __launch_bounds__(512, 2) void attn_kernel(
    const bf_t* __restrict__ qkv, const int* __restrict__ cu, int nseg,
    bf_t* __restrict__ outb)
{
  __shared__ __align__(16) bf_t Qs[128 * QSTR];
  __shared__ __align__(16) bf_t Ks[2][64 * QSTR];
  __shared__ __align__(16) bf_t VTs[2][80 * VSTR];
  __shared__ __align__(16) bf_t Pb[8][16 * PSTR];
  const int tid = threadIdx.x;
  const int l = tid & 63, w = tid >> 6;      // 8 waves
  const int lr = l & 15, lg = l >> 4;
  const int h = blockIdx.y;
  const int qbase = blockIdx.x * 128;

  int kstart = 0, kend = S_LEN;
  for (int s2 = 0; s2 < nseg; s2++) {
    int a = cu[s2], b = cu[s2 + 1];
    if (qbase >= a && qbase < b) { kstart = a; kend = b; }
  }

  for (int i = tid; i < 128 * QSTR; i += 512)
    if ((i % QSTR) >= HD) Qs[i] = 0;
  for (int i = tid; i < 64 * QSTR; i += 512)
    if ((i % QSTR) >= HD) { Ks[0][i] = 0; Ks[1][i] = 0; }
  for (int i = tid; i < 80 * VSTR; i += 512)
    if ((i / VSTR) >= HD) { VTs[0][i] = 0; VTs[1][i] = 0; }
  for (int c = tid; c < 1152; c += 512) {
    int r = c / 9, j = c % 9;
    *(s16x8*)&Qs[r * QSTR + j * 8] =
        *(const s16x8*)&qkv[(size_t)(qbase + r) * LD3 + h * HD + j * 8];
  }
  {
#pragma unroll
    for (int u = 0; u < 2; u++) {
      int c = tid + u * 512;
      if (c < 576) {
        int r = c / 9, j = c % 9;
        int gr = kstart + r; if (gr >= kend) gr = kend - 1;
        *(s16x8*)&Ks[0][r * QSTR + j * 8] =
            *(const s16x8*)&qkv[(size_t)gr * LD3 + HID + h * HD + j * 8];
      }
    }
#pragma unroll
    for (int u = 0; u < 2; u++) {
      int c = tid + u * 512;
      if (c < 576) {
        int r = c & 63, j = c >> 6;
        int gr = kstart + r; if (gr >= kend) gr = kend - 1;
        s16x8 v = *(const s16x8*)&qkv[(size_t)gr * LD3 + 2 * HID + h * HD + j * 8];
#pragma unroll
        for (int jj = 0; jj < 8; jj++) VTs[0][(j * 8 + jj) * VSTR + r] = v[jj];
      }
    }
  }
  __syncthreads();

  s16x8 qf[3];
#pragma unroll
  for (int ks = 0; ks < 3; ks++)
    qf[ks] = *(const s16x8*)&Qs[(w * 16 + lr) * QSTR + ks * 32 + lg * 8];

  float m_i[4], l_i[4];
  f32x4 Of[5] = {};
#pragma unroll
  for (int i = 0; i < 4; i++) { m_i[i] = -1e30f; l_i[i] = 0.0f; }

  const int ntile = (kend - kstart + 63) >> 6;
  int cur = 0;
  for (int t = 0; t < ntile; t++) {
    const int kb = kstart + t * 64;
    const bool more = (t + 1 < ntile);

    s16x8 kreg[2], vreg[2];
    if (more) {
      const int nb = kb + 64;
#pragma unroll
      for (int u = 0; u < 2; u++) {
        int c = tid + u * 512;
        if (c < 576) {
          int r = c / 9, j = c % 9;
          int gr = nb + r; if (gr >= kend) gr = kend - 1;
          kreg[u] = *(const s16x8*)&qkv[(size_t)gr * LD3 + HID + h * HD + j * 8];
        }
      }
#pragma unroll
      for (int u = 0; u < 2; u++) {
        int c = tid + u * 512;
        if (c < 576) {
          int r = c & 63, j = c >> 6;
          int gr = nb + r; if (gr >= kend) gr = kend - 1;
          vreg[u] = *(const s16x8*)&qkv[(size_t)gr * LD3 + 2 * HID + h * HD + j * 8];
        }
      }
    }

    f32x4 sc[4] = {};
#pragma unroll
    for (int kc = 0; kc < 4; kc++) {
#pragma unroll
      for (int ks = 0; ks < 3; ks++) {
        s16x8 kf = *(const s16x8*)&Ks[cur][(kc * 16 + lr) * QSTR + ks * 32 + lg * 8];
        sc[kc] = __builtin_amdgcn_mfma_f32_16x16x32_bf16(qf[ks], kf, sc[kc], 0, 0, 0);
      }
    }
#pragma unroll
    for (int kc = 0; kc < 4; kc++) {
      if ((kb + kc * 16 + lr) >= kend) {
#pragma unroll
        for (int i = 0; i < 4; i++) sc[kc][i] = -1e30f;
      }
    }
    float tmax[4], scl[4], rs[4];
#pragma unroll
    for (int i = 0; i < 4; i++) {
      float tm = fmaxf(fmaxf(sc[0][i], sc[1][i]), fmaxf(sc[2][i], sc[3][i]));
#pragma unroll
      for (int d2 = 1; d2 < 16; d2 <<= 1) tm = fmaxf(tm, __shfl_xor(tm, d2));
      tmax[i] = tm;
    }
#pragma unroll
    for (int i = 0; i < 4; i++) {
      float mn = fmaxf(m_i[i], tmax[i]);
      scl[i] = __expf(m_i[i] - mn);
      m_i[i] = mn;
      rs[i] = 0.0f;
    }
#pragma unroll
    for (int kc = 0; kc < 4; kc++)
#pragma unroll
      for (int i = 0; i < 4; i++) {
        float p = __expf(sc[kc][i] - m_i[i]);
        sc[kc][i] = p;
        rs[i] += p;
      }
#pragma unroll
    for (int i = 0; i < 4; i++) {
#pragma unroll
      for (int d2 = 1; d2 < 16; d2 <<= 1) rs[i] += __shfl_xor(rs[i], d2);
      l_i[i] = l_i[i] * scl[i] + rs[i];
    }
#pragma unroll
    for (int nt = 0; nt < 5; nt++)
#pragma unroll
      for (int i = 0; i < 4; i++) Of[nt][i] *= scl[i];
#pragma unroll
    for (int kc = 0; kc < 4; kc++)
#pragma unroll
      for (int i = 0; i < 4; i++)
        Pb[w][(lg * 4 + i) * PSTR + kc * 16 + lr] = f2b(sc[kc][i]);
    asm volatile("s_waitcnt lgkmcnt(0)" ::: "memory");
    __builtin_amdgcn_sched_barrier(0);
    s16x8 pf[2];
#pragma unroll
    for (int k2 = 0; k2 < 2; k2++)
      pf[k2] = *(const s16x8*)&Pb[w][lr * PSTR + k2 * 32 + lg * 8];
#pragma unroll
    for (int nt = 0; nt < 5; nt++) {
#pragma unroll
      for (int k2 = 0; k2 < 2; k2++) {
        const int vb = (nt * 16 + lr) * VSTR + k2 * 32 + lg * 8;
        s16x4 va = *(const s16x4*)&VTs[cur][vb];
        s16x4 vb2 = *(const s16x4*)&VTs[cur][vb + 4];
        s16x8 vf;
        vf[0] = va[0]; vf[1] = va[1]; vf[2] = va[2]; vf[3] = va[3];
        vf[4] = vb2[0]; vf[5] = vb2[1]; vf[6] = vb2[2]; vf[7] = vb2[3];
        Of[nt] = __builtin_amdgcn_mfma_f32_16x16x32_bf16(pf[k2], vf, Of[nt], 0, 0, 0);
      }
    }

    if (more) {
#pragma unroll
      for (int u = 0; u < 2; u++) {
        int c = tid + u * 512;
        if (c < 576) {
          int r = c / 9, j = c % 9;
          *(s16x8*)&Ks[cur ^ 1][r * QSTR + j * 8] = kreg[u];
        }
      }
#pragma unroll
      for (int u = 0; u < 2; u++) {
        int c = tid + u * 512;
        if (c < 576) {
          int r = c & 63, j = c >> 6;
#pragma unroll
          for (int jj = 0; jj < 8; jj++)
            VTs[cur ^ 1][(j * 8 + jj) * VSTR + r] = vreg[u][jj];
        }
      }
    }
    __syncthreads();
    cur ^= 1;
  }

  float inv[4];
#pragma unroll
  for (int i = 0; i < 4; i++) inv[i] = 1.0f / l_i[i];
#pragma unroll
  for (int nt = 0; nt < 5; nt++) {
    int cc = nt * 16 + lr;
    if (cc < HD) {
#pragma unroll
      for (int i = 0; i < 4; i++) {
        int row = qbase + w * 16 + lg * 4 + i;
        outb[(size_t)row * HID + h * HD + cc] = f2b(Of[nt][i] * inv[i]);
      }
    }
  }
}

// ---------------- host orchestration ----------------
extern "C" void kernel_launch(void* const* d_in, const int* in_sizes, int n_in,
                              void* d_out, int out_size, void* d_ws, size_t ws_size,
                              hipStream_t stream) {
  const float* x     = (const float*)d_in[0];
  const int*   cu    = (const int*)d_in[1];
  const float* rotab = (const float*)d_in[2];
  const float* n1w   = (const float*)d_in[3];
  const float* n1b   = (const float*)d_in[4];
  const float* qkvw  = (const float*)d_in[5];
  const float* qkvb  = (const float*)d_in[6];
  const float* projw = (const float*)d_in[7];
  const float* projb = (const float*)d_in[8];
  const float* n2w   = (const float*)d_in[9];
  const float* n2b   = (const float*)d_in[10];
  const float* fc1w  = (const float*)d_in[11];
  const float* fc1b  = (const float*)d_in[12];
  const float* fc2w  = (const float*)d_in[13];
  const float* fc2b  = (const float*)d_in[14];
  float* out = (float*)d_out;
  char* ws = (char*)d_ws;

  size_t off = 0;
  float* xbuf = (float*)(ws + off); off += (size_t)S_LEN * HID * 4;        // 9.44 MB
  bf_t* hbf   = (bf_t*)(ws + off);  off += (size_t)S_LEN * HID * 2;        // 4.72 MB
  bf_t* qkvbf = (bf_t*)(ws + off);                                          // shared slot
  bf_t* ff1bf = (bf_t*)(ws + off);  off += (size_t)S_LEN * FFP * 2;        // 17.7 MB
  bf_t* attnbf= (bf_t*)(ws + off);  off += (size_t)S_LEN * HID * 2;        // 4.72 MB
  bf_t* arena = (bf_t*)(ws + off);  off += (size_t)ARENA_ELEMS * 2;        // 30.6 MB
  float* ctab = (float*)(ws + off); off += (size_t)S_LEN * ROT * 4;
  float* stab = (float*)(ws + off); off += (size_t)S_LEN * ROT * 4;
  float* part = (float*)(ws + off); off += (size_t)4 * S_LEN * HID * 4;    // 37.75 MB

  costab_kernel<<<(S_LEN * ROT + 255) / 256, 256, 0, stream>>>(rotab, ctab, stab);

  const int nseg = in_sizes[1] - 1;

  for (int d = 0; d < 2; d++) {
    const float* xin = (d == 0) ? x : xbuf;   // residual spine source
    convw_all<<<(TOT_Q + 255) / 256, 256, 0, stream>>>(
        qkvw + (size_t)d * LD3 * HID, projw + (size_t)d * HID * HID,
        fc1w + (size_t)d * FF * HID, fc2w + (size_t)d * HID * FF, arena);
    if (d == 0)
      ln_kernel<<<S_LEN, 256, 0, stream>>>(x, n1w, n1b, hbf);
    // QKV: gemm2, grid 54x16 = 864 blocks
    gemm2<0><<<dim3(LD3 / 64, 16), 256, 0, stream>>>(
        hbf, HID, arena + QKV_OFF, HID, qkvb + (size_t)d * LD3, LD3,
        qkvbf, LD3, LD3, HID, HID);
    rotary_kernel<<<(S_LEN * HEADS * ROT + 255) / 256, 256, 0, stream>>>(qkvbf, ctab, stab);
    // attention: QBLK=128, grid 16x16 = 256 blocks (1/CU)
    attn_kernel<<<dim3(S_LEN / 128, HEADS), 512, 0, stream>>>(qkvbf, cu, nseg, attnbf);
    // proj: gemm1p (2-buf) split-K x4 (kchunk 288), grid 9x16x4 = 576
    gemm1p<<<dim3(HID / 128, 16, 4), 256, 0, stream>>>(
        attnbf, HID, arena + P_OFF, HID, part, HID, HID, 288);
    redln_kernel<<<S_LEN, 256, 0, stream>>>(
        part, projb + (size_t)d * HID, xin, xbuf, hbf,
        n2w + (size_t)d * HID, n2b + (size_t)d * HID, 1);
    // FC1 (+gelu): gemm2, grid 68x16 = 1088 (ceil(4320/64)=68)
    gemm2<2><<<dim3((FFP + 63) / 64, 16), 256, 0, stream>>>(
        hbf, HID, arena + F1_OFF, HID, fc1b + (size_t)d * FF, FF,
        ff1bf, FFP, FF, HID, HID);
    // FC2: gemm1p (2-buf) split-K x4 (K=4320, kchunk 1088), grid 9x16x4 = 576
    gemm1p<<<dim3(HID / 128, 16, 4), 256, 0, stream>>>(
        ff1bf, FFP, arena + F2_OFF, FFP, part, HID, FFP, 1088);
    if (d == 0) {
      redln_kernel<<<S_LEN, 256, 0, stream>>>(
          part, fc2b, xbuf, xbuf, hbf, n1w + HID, n1b + HID, 1);
    } else {
      redln_kernel<<<S_LEN, 256, 0, stream>>>(
          part, fc2b + (size_t)HID, xbuf, out, nullptr, nullptr, nullptr, 0);
    }
  }
}